// Round 14
// baseline (352.918 us; speedup 1.0000x reference)
//
#include <hip/hip_runtime.h>

// B=2, S=2048, E=512, H=8, D=64, MAX_SEQ=2048
// out0: (2,2048,512) floats at d_out;  attn: (2,8,2048,2048) at d_out+2097152

typedef __attribute__((ext_vector_type(4))) float f32x4;
typedef __attribute__((ext_vector_type(8))) short short8;

__device__ inline unsigned short f2bf(float x) {             // RTN-even fp32->bf16
    unsigned u = __float_as_uint(x);
    unsigned r = (u + 0x7fffu + ((u >> 16) & 1u)) >> 16;
    return (unsigned short)r;
}
__device__ inline float bf2f(unsigned short h) {
    return __uint_as_float(((unsigned)h) << 16);
}
// LDS swizzle for [rows][64] bf16 tiles (128 B rows), 16B-granule XOR
__device__ inline int swz(int row, int bytecol) {
    return (row << 7) + (bytecol ^ ((row & 7) << 4));
}
__device__ inline void cvt4(float4 v, uint2& hi, uint2& lo) {
    unsigned short h0 = f2bf(v.x), h1 = f2bf(v.y), h2 = f2bf(v.z), h3 = f2bf(v.w);
    hi = make_uint2(((unsigned)h1 << 16) | h0, ((unsigned)h3 << 16) | h2);
    lo = make_uint2(((unsigned)f2bf(v.y - bf2f(h1)) << 16) | f2bf(v.x - bf2f(h0)),
                    ((unsigned)f2bf(v.w - bf2f(h3)) << 16) | f2bf(v.z - bf2f(h2)));
}

// ---------------------------------------------------------------------------
// K0: weight prep — 4 x W(512x512) -> WT hi/lo bf16 planes [n][k], z selects
// ---------------------------------------------------------------------------
__global__ __launch_bounds__(256) void wt_prep4(const float* __restrict__ W0,
                                                const float* __restrict__ W1,
                                                const float* __restrict__ W2,
                                                const float* __restrict__ W3,
                                                unsigned short* __restrict__ wt)
{
    __shared__ float Ls[32][33];
    const int t = threadIdx.x;
    const int z = blockIdx.z;
    const float* W = (z == 0) ? W0 : (z == 1) ? W1 : (z == 2) ? W2 : W3;
    unsigned short* WTh = wt + (size_t)(2 * z) * 262144;
    unsigned short* WTl = wt + (size_t)(2 * z + 1) * 262144;
    const int k0 = blockIdx.x << 5, n0 = blockIdx.y << 5;
#pragma unroll
    for (int i = 0; i < 4; ++i) {
        int idx = (i << 8) + t;
        int kk = idx >> 5, nn = idx & 31;
        Ls[kk][nn] = W[(size_t)(k0 + kk) * 512 + n0 + nn];
    }
    __syncthreads();
#pragma unroll
    for (int i = 0; i < 2; ++i) {
        int idx = (i << 8) + t;
        int nn = idx >> 4, kp = idx & 15;
        float f0 = Ls[2 * kp][nn], f1 = Ls[2 * kp + 1][nn];
        unsigned short h0 = f2bf(f0), h1 = f2bf(f1);
        size_t off = (size_t)(n0 + nn) * 512 + k0 + 2 * kp;
        *(unsigned*)&WTh[off] = ((unsigned)h1 << 16) | h0;
        *(unsigned*)&WTl[off] = ((unsigned)f2bf(f1 - bf2f(h1)) << 16) | f2bf(f0 - bf2f(h0));
    }
}

// ---------------------------------------------------------------------------
// K0b: rel_emb (2048x64) -> hi bf16 plane
// ---------------------------------------------------------------------------
__global__ __launch_bounds__(256) void rel_prep(const float* __restrict__ rel,
                                                unsigned short* __restrict__ relh)
{
    int idx = (blockIdx.x * 256 + threadIdx.x) << 3;
    float4 a = *(const float4*)&rel[idx];
    float4 b = *(const float4*)&rel[idx + 4];
    uint4 o;
    o.x = ((unsigned)f2bf(a.y) << 16) | f2bf(a.x);
    o.y = ((unsigned)f2bf(a.w) << 16) | f2bf(a.z);
    o.z = ((unsigned)f2bf(b.y) << 16) | f2bf(b.x);
    o.w = ((unsigned)f2bf(b.w) << 16) | f2bf(b.z);
    *(uint4*)&relh[idx] = o;
}

// ---------------------------------------------------------------------------
// 64x64-tile split-bf16 GEMM core (qkv kernel).
// ---------------------------------------------------------------------------
__device__ __forceinline__ void gemm64_core(const float* __restrict__ A,
                                            const unsigned short* __restrict__ WTh,
                                            const unsigned short* __restrict__ WTl,
                                            int m0, int n0, char* smem, int t,
                                            f32x4 (&acc)[4])
{
    char* aH = smem;
    char* aL = smem + 8192;
    char* wH = smem + 16384;
    char* wL = smem + 24576;
    const int lane = t & 63, w = t >> 6;
    const int lr = lane & 15, kg = lane >> 4;

    for (int k0 = 0; k0 < 512; k0 += 64) {
        if (k0) __syncthreads();
#pragma unroll
        for (int i = 0; i < 4; ++i) {
            int idx = (i << 8) + t;
            int row = idx >> 4, c4 = idx & 15;
            float4 v = *(const float4*)&A[(size_t)(m0 + row) * 512 + k0 + (c4 << 2)];
            uint2 hi, lo; cvt4(v, hi, lo);
            int ph = swz(row, c4 << 3);
            *(uint2*)(aH + ph) = hi;
            *(uint2*)(aL + ph) = lo;
        }
#pragma unroll
        for (int i = 0; i < 4; ++i) {
            int idx = (i << 8) + t;
            int plane = idx >> 9, rem = idx & 511;
            int nn = rem >> 3, j8 = rem & 7;
            const unsigned short* src = plane ? WTl : WTh;
            uint4 vv = *(const uint4*)&src[(size_t)(n0 + nn) * 512 + k0 + (j8 << 3)];
            *(uint4*)((plane ? wL : wH) + swz(nn, j8 << 4)) = vv;
        }
        __syncthreads();
#pragma unroll
        for (int kk = 0; kk < 2; ++kk) {
            int bc = (kk << 6) + (kg << 4);
            int ar = (w << 4) + lr;
            short8 a_h = *(const short8*)(aH + swz(ar, bc));
            short8 a_l = *(const short8*)(aL + swz(ar, bc));
#pragma unroll
            for (int f = 0; f < 4; ++f) {
                short8 b_h = *(const short8*)(wH + swz((f << 4) + lr, bc));
                short8 b_l = *(const short8*)(wL + swz((f << 4) + lr, bc));
                acc[f] = __builtin_amdgcn_mfma_f32_16x16x32_bf16(a_h, b_h, acc[f], 0, 0, 0);
                acc[f] = __builtin_amdgcn_mfma_f32_16x16x32_bf16(a_l, b_h, acc[f], 0, 0, 0);
                acc[f] = __builtin_amdgcn_mfma_f32_16x16x32_bf16(a_h, b_l, acc[f], 0, 0, 0);
            }
        }
    }
}

// ---------------------------------------------------------------------------
// K1: batched QKV projections. z=0: q (BHSD planes), z=1: k (BHSD), z=2: v (BHDS).
// ---------------------------------------------------------------------------
__global__ __launch_bounds__(256) void gemm_qkv(
    const float* __restrict__ Aq, const float* __restrict__ Ak, const float* __restrict__ Av,
    const unsigned short* __restrict__ wt,
    const float* __restrict__ bq, const float* __restrict__ bk, const float* __restrict__ bv,
    unsigned short* __restrict__ qh, unsigned short* __restrict__ ql,
    unsigned short* __restrict__ kh, unsigned short* __restrict__ kl,
    unsigned short* __restrict__ vh, unsigned short* __restrict__ vl)
{
    __shared__ char smem[32768];
    const int t = threadIdx.x;
    const int z = blockIdx.z;
    const int n0 = blockIdx.x << 6;
    const int m0 = blockIdx.y << 6;
    const int lane = t & 63, w = t >> 6;
    const int lr = lane & 15, kg = lane >> 4;

    const float* A = (z == 0) ? Aq : (z == 1) ? Ak : Av;
    const float* bias = (z == 0) ? bq : (z == 1) ? bk : bv;
    const unsigned short* WTh = wt + (size_t)(2 * z) * 262144;
    const unsigned short* WTl = wt + (size_t)(2 * z + 1) * 262144;
    unsigned short* outH = (z == 0) ? qh : (z == 1) ? kh : vh;
    unsigned short* outL = (z == 0) ? ql : (z == 1) ? kl : vl;

    f32x4 acc[4];
#pragma unroll
    for (int f = 0; f < 4; ++f) acc[f] = {0.f, 0.f, 0.f, 0.f};

    gemm64_core(A, WTh, WTl, m0, n0, smem, t, acc);

    const int mbase = m0 + (w << 4) + (kg << 2);
    const int b = mbase >> 11, s = mbase & 2047;
    const int bidx = (b << 3) + (n0 >> 6);
#pragma unroll
    for (int f = 0; f < 4; ++f) {
        int d = (f << 4) + lr;
        float bv_ = bias[n0 + d];
        if (z < 2) {   // BHSD scalar stores
#pragma unroll
            for (int e = 0; e < 4; ++e) {
                float val = acc[f][e] + bv_;
                unsigned short hh = f2bf(val);
                size_t off = ((size_t)bidx * 2048 + s + e) * 64 + d;
                outH[off] = hh;
                outL[off] = f2bf(val - bf2f(hh));
            }
        } else {       // BHDS vector stores
            unsigned short h[4], l[4];
#pragma unroll
            for (int e = 0; e < 4; ++e) {
                float val = acc[f][e] + bv_;
                h[e] = f2bf(val);
                l[e] = f2bf(val - bf2f(h[e]));
            }
            size_t off = ((size_t)bidx * 64 + d) * 2048 + s;
            *(uint2*)&outH[off] = make_uint2(((unsigned)h[1] << 16) | h[0],
                                             ((unsigned)h[3] << 16) | h[2]);
            *(uint2*)&outL[off] = make_uint2(((unsigned)l[1] << 16) | l[0],
                                             ((unsigned)l[3] << 16) | l[2]);
        }
    }
}

// ---------------------------------------------------------------------------
// K5: final projection — A = pO chunk0 + chunk1 summed in staging.
// ---------------------------------------------------------------------------
__global__ __launch_bounds__(256) void gemm_out(
    const float* __restrict__ pO,
    const unsigned short* __restrict__ WTh, const unsigned short* __restrict__ WTl,
    const float* __restrict__ bias, float* __restrict__ out0)
{
    __shared__ char smem[32768];
    char* aH = smem;
    char* aL = smem + 8192;
    char* wH = smem + 16384;
    char* wL = smem + 24576;
    const int t = threadIdx.x;
    const int n0 = blockIdx.x << 6;
    const int m0 = blockIdx.y << 6;
    const int lane = t & 63, w = t >> 6;
    const int lr = lane & 15, kg = lane >> 4;
    const int bq = m0 >> 11, s0 = m0 & 2047;

    f32x4 acc[4];
#pragma unroll
    for (int f = 0; f < 4; ++f) acc[f] = {0.f, 0.f, 0.f, 0.f};

    for (int k0 = 0; k0 < 512; k0 += 64) {
        if (k0) __syncthreads();
        // stage A: sum the two pO chunks, cvt to hi/lo bf16
        const float* p0 = pO + ((size_t)((bq << 3) + (k0 >> 6)) * 2048 + s0) * 64;
#pragma unroll
        for (int i = 0; i < 2; ++i) {
            int idx = (i << 8) + t;            // 0..511 = 64 rows x 8 groups
            int row = idx >> 3, j8 = idx & 7;
            size_t off = (size_t)row * 64 + (j8 << 3);
            float4 a0 = *(const float4*)&p0[off];
            float4 a1 = *(const float4*)&p0[off + 4];
            float4 b0 = *(const float4*)&p0[off + 2097152];
            float4 b1 = *(const float4*)&p0[off + 4 + 2097152];
            float4 v0 = make_float4(a0.x + b0.x, a0.y + b0.y, a0.z + b0.z, a0.w + b0.w);
            float4 v1 = make_float4(a1.x + b1.x, a1.y + b1.y, a1.z + b1.z, a1.w + b1.w);
            uint2 h0, l0, h1, l1;
            cvt4(v0, h0, l0);
            cvt4(v1, h1, l1);
            int ph = swz(row, j8 << 4);
            *(uint4*)(aH + ph) = make_uint4(h0.x, h0.y, h1.x, h1.y);
            *(uint4*)(aL + ph) = make_uint4(l0.x, l0.y, l1.x, l1.y);
        }
#pragma unroll
        for (int i = 0; i < 4; ++i) {   // W planes
            int idx = (i << 8) + t;
            int plane = idx >> 9, rem = idx & 511;
            int nn = rem >> 3, j8 = rem & 7;
            const unsigned short* src = plane ? WTl : WTh;
            uint4 vv = *(const uint4*)&src[(size_t)(n0 + nn) * 512 + k0 + (j8 << 3)];
            *(uint4*)((plane ? wL : wH) + swz(nn, j8 << 4)) = vv;
        }
        __syncthreads();
#pragma unroll
        for (int kk = 0; kk < 2; ++kk) {
            int bc = (kk << 6) + (kg << 4);
            int ar = (w << 4) + lr;
            short8 a_h = *(const short8*)(aH + swz(ar, bc));
            short8 a_l = *(const short8*)(aL + swz(ar, bc));
#pragma unroll
            for (int f = 0; f < 4; ++f) {
                short8 b_h = *(const short8*)(wH + swz((f << 4) + lr, bc));
                short8 b_l = *(const short8*)(wL + swz((f << 4) + lr, bc));
                acc[f] = __builtin_amdgcn_mfma_f32_16x16x32_bf16(a_h, b_h, acc[f], 0, 0, 0);
                acc[f] = __builtin_amdgcn_mfma_f32_16x16x32_bf16(a_l, b_h, acc[f], 0, 0, 0);
                acc[f] = __builtin_amdgcn_mfma_f32_16x16x32_bf16(a_h, b_l, acc[f], 0, 0, 0);
            }
        }
    }

    const int mbase = m0 + (w << 4) + (kg << 2);
#pragma unroll
    for (int f = 0; f < 4; ++f) {
        int n = n0 + (f << 4) + lr;
        float bv = bias[n];
#pragma unroll
        for (int e = 0; e < 4; ++e)
            out0[(size_t)(mbase + e) * 512 + n] = acc[f][e] + bv;
    }
}

// ---------------------------------------------------------------------------
// K2: flash-style logits, swapped MFMA operands + merged stats barrier
// (verified round 13).
// ---------------------------------------------------------------------------
__global__ __launch_bounds__(512, 4) void logits_flash(
    const unsigned short* __restrict__ qh_g, const unsigned short* __restrict__ ql_g,
    const unsigned short* __restrict__ kh_g, const unsigned short* __restrict__ kl_g,
    const unsigned short* __restrict__ relh_g,
    float* __restrict__ attn, float2* __restrict__ stats)
{
    __shared__ char smem[59136];
    char* kh = smem;                              // [128][64] swz bf16 (16 KB)
    char* kl = smem + 16384;
    char* bandP = smem + 32768;                   // band [192][64] swz bf16
    unsigned short* Pt = (unsigned short*)(smem + 32768);  // [192][66] bf16, overlays band
    float* part_m = (float*)(smem + 58112);       // [2][64]
    float* part_z = (float*)(smem + 58624);       // [2][64]

    const int t = threadIdx.x;
    const int bh = blockIdx.y;
    int ib = blockIdx.x; if (bh & 8) ib = 31 - ib;
    const int i0 = ib << 6;
    const int lane = t & 63, w = t >> 6;
    const int wr = w >> 1, wc = w & 1;
    const int lr = lane & 15, kg = lane >> 4;
    const int irow = (wr << 4) + lr;

    const size_t qoff = ((size_t)bh * 2048 + i0 + irow) * 64;
    const short8 aH0 = *(const short8*)(qh_g + qoff + (kg << 3));
    const short8 aH1 = *(const short8*)(qh_g + qoff + 32 + (kg << 3));
    const short8 aL0 = *(const short8*)(ql_g + qoff + (kg << 3));
    const short8 aL1 = *(const short8*)(ql_g + qoff + 32 + (kg << 3));

    float rm = -3.0e38f, rz = 0.f;

    const unsigned short* khb = kh_g + (size_t)bh * 2048 * 64;
    const unsigned short* klb = kl_g + (size_t)bh * 2048 * 64;
    const size_t obase = ((size_t)bh * 2048 + i0) * 2048;

    for (int jt = 0; jt < 16; ++jt) {
        const int j0 = jt << 7;
        const bool anyRel = (j0 <= i0 + 63);
        const int m0 = 1984 - i0 + j0;
        __syncthreads();   // prior iter LDS reads done; prev parts visible
        if (jt > 0 && t < 64) {   // wave0: combine prev tile's stats
            float m1 = part_m[t], m2 = part_m[64 + t];
            float z1 = part_z[t], z2 = part_z[64 + t];
            float tm = fmaxf(m1, m2);
            float tz = z1 * __expf((m1 - tm) * 0.125f) + z2 * __expf((m2 - tm) * 0.125f);
            float mn = fmaxf(rm, tm);
            rz = rz * __expf((rm - mn) * 0.125f) + tz * __expf((tm - mn) * 0.125f);
            rm = mn;
        }
        {
            int rr = t >> 2, gp = (t & 3) << 1;
            const unsigned short* s0 = khb + (size_t)(j0 + rr) * 64 + (gp << 3);
            *(uint4*)(kh + swz(rr, gp << 4)) = *(const uint4*)s0;
            *(uint4*)(kh + swz(rr, (gp + 1) << 4)) = *(const uint4*)(s0 + 8);
            const unsigned short* s1 = klb + (size_t)(j0 + rr) * 64 + (gp << 3);
            *(uint4*)(kl + swz(rr, gp << 4)) = *(const uint4*)s1;
            *(uint4*)(kl + swz(rr, (gp + 1) << 4)) = *(const uint4*)(s1 + 8);
        }
        if (anyRel) {
#pragma unroll
            for (int i = 0; i < 3; ++i) {
                int idx = (i << 9) + t;
                int row = idx >> 3, g = idx & 7;
                int m = m0 + row; if (m > 2047) m = 2047;
                *(uint4*)(bandP + swz(row, g << 4)) = *(const uint4*)(relh_g + (size_t)m * 64 + (g << 3));
            }
        }
        __syncthreads();

        f32x4 acc[4];
#pragma unroll
        for (int cf = 0; cf < 4; ++cf) {
            int krow = (wc << 6) + (cf << 4) + lr;
            short8 bH0 = *(const short8*)(kh + swz(krow, kg << 4));
            short8 bH1 = *(const short8*)(kh + swz(krow, 64 + (kg << 4)));
            short8 bL0 = *(const short8*)(kl + swz(krow, kg << 4));
            short8 bL1 = *(const short8*)(kl + swz(krow, 64 + (kg << 4)));
            f32x4 c = {0.f, 0.f, 0.f, 0.f};
            c = __builtin_amdgcn_mfma_f32_16x16x32_bf16(bH0, aH0, c, 0, 0, 0);
            c = __builtin_amdgcn_mfma_f32_16x16x32_bf16(bH1, aH1, c, 0, 0, 0);
            c = __builtin_amdgcn_mfma_f32_16x16x32_bf16(bH0, aL0, c, 0, 0, 0);
            c = __builtin_amdgcn_mfma_f32_16x16x32_bf16(bH1, aL1, c, 0, 0, 0);
            c = __builtin_amdgcn_mfma_f32_16x16x32_bf16(bL0, aH0, c, 0, 0, 0);
            c = __builtin_amdgcn_mfma_f32_16x16x32_bf16(bL1, aH1, c, 0, 0, 0);
            acc[cf] = c;
        }
        if (anyRel) {
            f32x4 pr[6];
#pragma unroll
            for (int q = 0; q < 6; ++q) {
                int ff = (wc ? 6 : 0) + q;
                int brow = (ff << 4) + lr;
                short8 rb0 = *(const short8*)(bandP + swz(brow, kg << 4));
                short8 rb1 = *(const short8*)(bandP + swz(brow, 64 + (kg << 4)));
                f32x4 c = {0.f, 0.f, 0.f, 0.f};
                c = __builtin_amdgcn_mfma_f32_16x16x32_bf16(rb0, aH0, c, 0, 0, 0);
                c = __builtin_amdgcn_mfma_f32_16x16x32_bf16(rb1, aH1, c, 0, 0, 0);
                pr[q] = c;
            }
            __syncthreads();
#pragma unroll
            for (int q = 0; q < 6; ++q) {
                int ff = (wc ? 6 : 0) + q;
#pragma unroll
                for (int e = 0; e < 4; ++e)
                    Pt[((ff << 4) + (kg << 2) + e) * 66 + irow] = f2bf(pr[q][e]);
            }
            __syncthreads();
        }

        float rowmax = -3.0e38f;
#pragma unroll
        for (int cf = 0; cf < 4; ++cf) {
            int jl0 = (wc << 6) + (cf << 4) + (kg << 2);
            f32x4 a = acc[cf];
#pragma unroll
            for (int e = 0; e < 4; ++e) {
                int jl = jl0 + e;
                if (anyRel && (jl - irow) <= (i0 - j0))
                    a[e] += bf2f(Pt[(jl + 63 - irow) * 66 + irow]);
            }
            acc[cf] = a;
            *(float4*)&attn[obase + (size_t)irow * 2048 + j0 + jl0] =
                make_float4(a[0], a[1], a[2], a[3]);
            rowmax = fmaxf(rowmax, fmaxf(fmaxf(a[0], a[1]), fmaxf(a[2], a[3])));
        }
        rowmax = fmaxf(rowmax, __shfl_xor(rowmax, 16, 64));
        rowmax = fmaxf(rowmax, __shfl_xor(rowmax, 32, 64));
        float zs = 0.f;
#pragma unroll
        for (int cf = 0; cf < 4; ++cf)
#pragma unroll
            for (int e = 0; e < 4; ++e)
                zs += __expf((acc[cf][e] - rowmax) * 0.125f);
        zs += __shfl_xor(zs, 16, 64);
        zs += __shfl_xor(zs, 32, 64);
        if (lane < 16) {
            part_m[(wc << 6) + irow] = rowmax;
            part_z[(wc << 6) + irow] = zs;
        }
        // no stats barrier: combined after next iteration's top barrier
    }
    __syncthreads();
    if (t < 64) {   // combine last tile + write stats
        float m1 = part_m[t], m2 = part_m[64 + t];
        float z1 = part_z[t], z2 = part_z[64 + t];
        float tm = fmaxf(m1, m2);
        float tz = z1 * __expf((m1 - tm) * 0.125f) + z2 * __expf((m2 - tm) * 0.125f);
        float mn = fmaxf(rm, tm);
        rz = rz * __expf((rm - mn) * 0.125f) + tz * __expf((tm - mn) * 0.125f);
        rm = mn;
        stats[bh * 2048 + i0 + t] = make_float2(rm, 1.0f / rz);
    }
}

// ---------------------------------------------------------------------------
// K4: fused normalize + attn write + PV MFMA — i-tile 32 for occupancy.
// LDS 24.25 KB -> 6 blocks/CU = 24 waves/CU (was 33 KB -> 3 blocks = 12
// waves, occupancy 38%, latency-bound at 2 barriers/tile). Wave grid 2x2:
// wave w handles rows ((w&1)<<4)..+15, V cols ((w>>1)<<5)..+31.
// ---------------------------------------------------------------------------
__global__ __launch_bounds__(256) void pv_fused(float* __restrict__ attn,
                                                const unsigned short* __restrict__ vTh,
                                                const unsigned short* __restrict__ vTl,
                                                const float2* __restrict__ stats,
                                                float* __restrict__ pO)
{
    __shared__ char smem[24832];
    char* pH = smem;              // [32][64] bf16 swz (4 KB)
    char* pL = smem + 4096;
    char* vH = smem + 8192;       // [64][64] bf16 swz (8 KB)
    char* vL = smem + 16384;
    float2* sm = (float2*)(smem + 24576);  // [32] row stats

    const int t = threadIdx.x;
    const int i0 = blockIdx.x << 5;
    const int bh = blockIdx.y;
    const int jc = blockIdx.z;
    const int jc0 = jc << 10;
    const int lane = t & 63, w = t >> 6;
    const int lr = lane & 15, kg = lane >> 4;
    const int wr = (w & 1) << 4;       // row half
    const int wc2 = (w >> 1) << 5;     // col half (V d)

    float* ab = attn + ((size_t)bh * 2048 + i0) * 2048;
    const unsigned short* vhb = vTh + (size_t)bh * 64 * 2048;
    const unsigned short* vlb = vTl + (size_t)bh * 64 * 2048;

    if (t < 32) sm[t] = stats[bh * 2048 + i0 + t];
    __syncthreads();

    f32x4 acc[2];
#pragma unroll
    for (int f = 0; f < 2; ++f) acc[f] = {0.f, 0.f, 0.f, 0.f};

    for (int j0 = jc0; j0 < jc0 + 1024; j0 += 64) {
        if (j0 != jc0) __syncthreads();
        // stage p (32 rows x 64 cols): normalize, write back, convert hi/lo
#pragma unroll
        for (int i = 0; i < 2; ++i) {
            int idx = (i << 8) + t;
            int row = idx >> 4, c4 = idx & 15;
            size_t go = (size_t)row * 2048 + j0 + (c4 << 2);
            float4 x = *(const float4*)&ab[go];
            float2 s2 = sm[row];
            float4 p;
            p.x = __expf((x.x - s2.x) * 0.125f) * s2.y;
            p.y = __expf((x.y - s2.x) * 0.125f) * s2.y;
            p.z = __expf((x.z - s2.x) * 0.125f) * s2.y;
            p.w = __expf((x.w - s2.x) * 0.125f) * s2.y;
            *(float4*)&ab[go] = p;
            uint2 hi, lo; cvt4(p, hi, lo);
            int ph = swz(row, c4 << 3);
            *(uint2*)(pH + ph) = hi;
            *(uint2*)(pL + ph) = lo;
        }
        // stage v^T chunk (64 d x 64 j, both planes): direct uint4 copies
#pragma unroll
        for (int i = 0; i < 4; ++i) {
            int idx = (i << 8) + t;
            int plane = idx >> 9, rem = idx & 511;
            int d = rem >> 3, g8 = rem & 7;
            const unsigned short* src = (plane ? vlb : vhb) + (size_t)d * 2048 + j0 + (g8 << 3);
            *(uint4*)((plane ? vL : vH) + swz(d, g8 << 4)) = *(const uint4*)src;
        }
        __syncthreads();
#pragma unroll
        for (int kk = 0; kk < 2; ++kk) {
            int bc = (kk << 6) + (kg << 4);
            int ar = wr + lr;
            short8 a_h = *(const short8*)(pH + swz(ar, bc));
            short8 a_l = *(const short8*)(pL + swz(ar, bc));
#pragma unroll
            for (int f = 0; f < 2; ++f) {
                int vrow = wc2 + (f << 4) + lr;
                short8 b_h = *(const short8*)(vH + swz(vrow, bc));
                short8 b_l = *(const short8*)(vL + swz(vrow, bc));
                acc[f] = __builtin_amdgcn_mfma_f32_16x16x32_bf16(a_h, b_h, acc[f], 0, 0, 0);
                acc[f] = __builtin_amdgcn_mfma_f32_16x16x32_bf16(a_l, b_h, acc[f], 0, 0, 0);
                acc[f] = __builtin_amdgcn_mfma_f32_16x16x32_bf16(a_h, b_l, acc[f], 0, 0, 0);
            }
        }
    }
    // partial O: pO[jc][bh][i][d]; D row = 4kg+e (p-row wr+..), col = lr (V d)
#pragma unroll
    for (int f = 0; f < 2; ++f) {
#pragma unroll
        for (int e = 0; e < 4; ++e) {
            int m = i0 + wr + (kg << 2) + e;
            pO[(size_t)jc * 2097152 + ((size_t)bh * 2048 + m) * 64 + wc2 + (f << 4) + lr] = acc[f][e];
        }
    }
}

// ---------------------------------------------------------------------------
extern "C" void kernel_launch(void* const* d_in, const int* in_sizes, int n_in,
                              void* d_out, int out_size, void* d_ws, size_t ws_size,
                              hipStream_t stream)
{
    const float* q_in = (const float*)d_in[0];
    const float* k_in = (const float*)d_in[1];
    const float* v_in = (const float*)d_in[2];
    const float* Wq   = (const float*)d_in[3];
    const float* bq   = (const float*)d_in[4];
    const float* Wk   = (const float*)d_in[5];
    const float* bk   = (const float*)d_in[6];
    const float* Wv   = (const float*)d_in[7];
    const float* bv   = (const float*)d_in[8];
    const float* Wo   = (const float*)d_in[9];
    const float* bo   = (const float*)d_in[10];
    const float* rel  = (const float*)d_in[11];

    float* out0 = (float*)d_out;
    float* attn = out0 + 2097152;

    float* ws = (float*)d_ws;
    // bf16 planes: each 2,097,152 ushorts = 1,048,576 FLOATS of ws
    unsigned short* qh = (unsigned short*)ws;                 // floats [0, 1M)
    unsigned short* ql = qh + 2097152;                        // floats [1M, 2M)
    unsigned short* kh = (unsigned short*)(ws + 2097152);     // floats [2M, 3M)
    unsigned short* kl = kh + 2097152;                        // floats [3M, 4M)
    unsigned short* vTh = (unsigned short*)(ws + 4194304);    // floats [4M, 5M)
    unsigned short* vTl = vTh + 2097152;                      // floats [5M, 6M)
    unsigned short* wt = (unsigned short*)(ws + 6291456);     // floats [6M, 7M)
    unsigned short* relh = (unsigned short*)(ws + 7340032);   // floats [7340032, 7405568)
    float2* stats = (float2*)(ws + 7405568);                  // floats [7405568, 7471104)
    float* pO = ws;                                           // 2 x 2,097,152 floats over dead q/k planes

    wt_prep4<<<dim3(16, 16, 4), 256, 0, stream>>>(Wq, Wk, Wv, Wo, wt);
    rel_prep<<<64, 256, 0, stream>>>(rel, relh);

    gemm_qkv<<<dim3(8, 64, 3), 256, 0, stream>>>(q_in, k_in, v_in, wt,
                                                 bq, bk, bv,
                                                 qh, ql, kh, kl, vTh, vTl);

    logits_flash<<<dim3(32, 16), 512, 0, stream>>>(qh, ql, kh, kl, relh, attn, stats);
    pv_fused<<<dim3(64, 16, 2), 256, 0, stream>>>(attn, vTh, vTl, stats, pO);

    gemm_out<<<dim3(8, 64), 256, 0, stream>>>(pO,
                                              wt + 6 * 262144, wt + 7 * 262144,
                                              bo, out0);
}

// Round 15
// 318.990 us; speedup vs baseline: 1.1064x; 1.1064x over previous
//
#include <hip/hip_runtime.h>

// B=2, S=2048, E=512, H=8, D=64, MAX_SEQ=2048
// out0: (2,2048,512) floats at d_out;  attn: (2,8,2048,2048) at d_out+2097152

typedef __attribute__((ext_vector_type(4))) float f32x4;
typedef __attribute__((ext_vector_type(8))) short short8;

__device__ inline unsigned short f2bf(float x) {             // RTN-even fp32->bf16
    unsigned u = __float_as_uint(x);
    unsigned r = (u + 0x7fffu + ((u >> 16) & 1u)) >> 16;
    return (unsigned short)r;
}
__device__ inline float bf2f(unsigned short h) {
    return __uint_as_float(((unsigned)h) << 16);
}
// LDS swizzle for [rows][64] bf16 tiles (128 B rows), 16B-granule XOR
__device__ inline int swz(int row, int bytecol) {
    return (row << 7) + (bytecol ^ ((row & 7) << 4));
}
__device__ inline void cvt4(float4 v, uint2& hi, uint2& lo) {
    unsigned short h0 = f2bf(v.x), h1 = f2bf(v.y), h2 = f2bf(v.z), h3 = f2bf(v.w);
    hi = make_uint2(((unsigned)h1 << 16) | h0, ((unsigned)h3 << 16) | h2);
    lo = make_uint2(((unsigned)f2bf(v.y - bf2f(h1)) << 16) | f2bf(v.x - bf2f(h0)),
                    ((unsigned)f2bf(v.w - bf2f(h3)) << 16) | f2bf(v.z - bf2f(h2)));
}

// ---------------------------------------------------------------------------
// K0: weight prep — 4 x W(512x512) -> WT hi/lo bf16 planes [n][k], z selects
// ---------------------------------------------------------------------------
__global__ __launch_bounds__(256) void wt_prep4(const float* __restrict__ W0,
                                                const float* __restrict__ W1,
                                                const float* __restrict__ W2,
                                                const float* __restrict__ W3,
                                                unsigned short* __restrict__ wt)
{
    __shared__ float Ls[32][33];
    const int t = threadIdx.x;
    const int z = blockIdx.z;
    const float* W = (z == 0) ? W0 : (z == 1) ? W1 : (z == 2) ? W2 : W3;
    unsigned short* WTh = wt + (size_t)(2 * z) * 262144;
    unsigned short* WTl = wt + (size_t)(2 * z + 1) * 262144;
    const int k0 = blockIdx.x << 5, n0 = blockIdx.y << 5;
#pragma unroll
    for (int i = 0; i < 4; ++i) {
        int idx = (i << 8) + t;
        int kk = idx >> 5, nn = idx & 31;
        Ls[kk][nn] = W[(size_t)(k0 + kk) * 512 + n0 + nn];
    }
    __syncthreads();
#pragma unroll
    for (int i = 0; i < 2; ++i) {
        int idx = (i << 8) + t;
        int nn = idx >> 4, kp = idx & 15;
        float f0 = Ls[2 * kp][nn], f1 = Ls[2 * kp + 1][nn];
        unsigned short h0 = f2bf(f0), h1 = f2bf(f1);
        size_t off = (size_t)(n0 + nn) * 512 + k0 + 2 * kp;
        *(unsigned*)&WTh[off] = ((unsigned)h1 << 16) | h0;
        *(unsigned*)&WTl[off] = ((unsigned)f2bf(f1 - bf2f(h1)) << 16) | f2bf(f0 - bf2f(h0));
    }
}

// ---------------------------------------------------------------------------
// K0b: rel_emb (2048x64) -> hi bf16 plane
// ---------------------------------------------------------------------------
__global__ __launch_bounds__(256) void rel_prep(const float* __restrict__ rel,
                                                unsigned short* __restrict__ relh)
{
    int idx = (blockIdx.x * 256 + threadIdx.x) << 3;
    float4 a = *(const float4*)&rel[idx];
    float4 b = *(const float4*)&rel[idx + 4];
    uint4 o;
    o.x = ((unsigned)f2bf(a.y) << 16) | f2bf(a.x);
    o.y = ((unsigned)f2bf(a.w) << 16) | f2bf(a.z);
    o.z = ((unsigned)f2bf(b.y) << 16) | f2bf(b.x);
    o.w = ((unsigned)f2bf(b.w) << 16) | f2bf(b.z);
    *(uint4*)&relh[idx] = o;
}

// ---------------------------------------------------------------------------
// 64x64-tile split-bf16 GEMM core (qkv kernel).
// ---------------------------------------------------------------------------
__device__ __forceinline__ void gemm64_core(const float* __restrict__ A,
                                            const unsigned short* __restrict__ WTh,
                                            const unsigned short* __restrict__ WTl,
                                            int m0, int n0, char* smem, int t,
                                            f32x4 (&acc)[4])
{
    char* aH = smem;
    char* aL = smem + 8192;
    char* wH = smem + 16384;
    char* wL = smem + 24576;
    const int lane = t & 63, w = t >> 6;
    const int lr = lane & 15, kg = lane >> 4;

    for (int k0 = 0; k0 < 512; k0 += 64) {
        if (k0) __syncthreads();
#pragma unroll
        for (int i = 0; i < 4; ++i) {
            int idx = (i << 8) + t;
            int row = idx >> 4, c4 = idx & 15;
            float4 v = *(const float4*)&A[(size_t)(m0 + row) * 512 + k0 + (c4 << 2)];
            uint2 hi, lo; cvt4(v, hi, lo);
            int ph = swz(row, c4 << 3);
            *(uint2*)(aH + ph) = hi;
            *(uint2*)(aL + ph) = lo;
        }
#pragma unroll
        for (int i = 0; i < 4; ++i) {
            int idx = (i << 8) + t;
            int plane = idx >> 9, rem = idx & 511;
            int nn = rem >> 3, j8 = rem & 7;
            const unsigned short* src = plane ? WTl : WTh;
            uint4 vv = *(const uint4*)&src[(size_t)(n0 + nn) * 512 + k0 + (j8 << 3)];
            *(uint4*)((plane ? wL : wH) + swz(nn, j8 << 4)) = vv;
        }
        __syncthreads();
#pragma unroll
        for (int kk = 0; kk < 2; ++kk) {
            int bc = (kk << 6) + (kg << 4);
            int ar = (w << 4) + lr;
            short8 a_h = *(const short8*)(aH + swz(ar, bc));
            short8 a_l = *(const short8*)(aL + swz(ar, bc));
#pragma unroll
            for (int f = 0; f < 4; ++f) {
                short8 b_h = *(const short8*)(wH + swz((f << 4) + lr, bc));
                short8 b_l = *(const short8*)(wL + swz((f << 4) + lr, bc));
                acc[f] = __builtin_amdgcn_mfma_f32_16x16x32_bf16(a_h, b_h, acc[f], 0, 0, 0);
                acc[f] = __builtin_amdgcn_mfma_f32_16x16x32_bf16(a_l, b_h, acc[f], 0, 0, 0);
                acc[f] = __builtin_amdgcn_mfma_f32_16x16x32_bf16(a_h, b_l, acc[f], 0, 0, 0);
            }
        }
    }
}

// ---------------------------------------------------------------------------
// K1: batched QKV projections. z=0: q (BHSD planes), z=1: k (BHSD), z=2: v (BHDS).
// ---------------------------------------------------------------------------
__global__ __launch_bounds__(256) void gemm_qkv(
    const float* __restrict__ Aq, const float* __restrict__ Ak, const float* __restrict__ Av,
    const unsigned short* __restrict__ wt,
    const float* __restrict__ bq, const float* __restrict__ bk, const float* __restrict__ bv,
    unsigned short* __restrict__ qh, unsigned short* __restrict__ ql,
    unsigned short* __restrict__ kh, unsigned short* __restrict__ kl,
    unsigned short* __restrict__ vh, unsigned short* __restrict__ vl)
{
    __shared__ char smem[32768];
    const int t = threadIdx.x;
    const int z = blockIdx.z;
    const int n0 = blockIdx.x << 6;
    const int m0 = blockIdx.y << 6;
    const int lane = t & 63, w = t >> 6;
    const int lr = lane & 15, kg = lane >> 4;

    const float* A = (z == 0) ? Aq : (z == 1) ? Ak : Av;
    const float* bias = (z == 0) ? bq : (z == 1) ? bk : bv;
    const unsigned short* WTh = wt + (size_t)(2 * z) * 262144;
    const unsigned short* WTl = wt + (size_t)(2 * z + 1) * 262144;
    unsigned short* outH = (z == 0) ? qh : (z == 1) ? kh : vh;
    unsigned short* outL = (z == 0) ? ql : (z == 1) ? kl : vl;

    f32x4 acc[4];
#pragma unroll
    for (int f = 0; f < 4; ++f) acc[f] = {0.f, 0.f, 0.f, 0.f};

    gemm64_core(A, WTh, WTl, m0, n0, smem, t, acc);

    const int mbase = m0 + (w << 4) + (kg << 2);
    const int b = mbase >> 11, s = mbase & 2047;
    const int bidx = (b << 3) + (n0 >> 6);
#pragma unroll
    for (int f = 0; f < 4; ++f) {
        int d = (f << 4) + lr;
        float bv_ = bias[n0 + d];
        if (z < 2) {   // BHSD scalar stores
#pragma unroll
            for (int e = 0; e < 4; ++e) {
                float val = acc[f][e] + bv_;
                unsigned short hh = f2bf(val);
                size_t off = ((size_t)bidx * 2048 + s + e) * 64 + d;
                outH[off] = hh;
                outL[off] = f2bf(val - bf2f(hh));
            }
        } else {       // BHDS vector stores
            unsigned short h[4], l[4];
#pragma unroll
            for (int e = 0; e < 4; ++e) {
                float val = acc[f][e] + bv_;
                h[e] = f2bf(val);
                l[e] = f2bf(val - bf2f(h[e]));
            }
            size_t off = ((size_t)bidx * 64 + d) * 2048 + s;
            *(uint2*)&outH[off] = make_uint2(((unsigned)h[1] << 16) | h[0],
                                             ((unsigned)h[3] << 16) | h[2]);
            *(uint2*)&outL[off] = make_uint2(((unsigned)l[1] << 16) | l[0],
                                             ((unsigned)l[3] << 16) | l[2]);
        }
    }
}

// ---------------------------------------------------------------------------
// K5: final projection — A = pO chunk0 + chunk1 summed in staging.
// ---------------------------------------------------------------------------
__global__ __launch_bounds__(256) void gemm_out(
    const float* __restrict__ pO,
    const unsigned short* __restrict__ WTh, const unsigned short* __restrict__ WTl,
    const float* __restrict__ bias, float* __restrict__ out0)
{
    __shared__ char smem[32768];
    char* aH = smem;
    char* aL = smem + 8192;
    char* wH = smem + 16384;
    char* wL = smem + 24576;
    const int t = threadIdx.x;
    const int n0 = blockIdx.x << 6;
    const int m0 = blockIdx.y << 6;
    const int lane = t & 63, w = t >> 6;
    const int lr = lane & 15, kg = lane >> 4;
    const int bq = m0 >> 11, s0 = m0 & 2047;

    f32x4 acc[4];
#pragma unroll
    for (int f = 0; f < 4; ++f) acc[f] = {0.f, 0.f, 0.f, 0.f};

    for (int k0 = 0; k0 < 512; k0 += 64) {
        if (k0) __syncthreads();
        const float* p0 = pO + ((size_t)((bq << 3) + (k0 >> 6)) * 2048 + s0) * 64;
#pragma unroll
        for (int i = 0; i < 2; ++i) {
            int idx = (i << 8) + t;
            int row = idx >> 3, j8 = idx & 7;
            size_t off = (size_t)row * 64 + (j8 << 3);
            float4 a0 = *(const float4*)&p0[off];
            float4 a1 = *(const float4*)&p0[off + 4];
            float4 b0 = *(const float4*)&p0[off + 2097152];
            float4 b1 = *(const float4*)&p0[off + 4 + 2097152];
            float4 v0 = make_float4(a0.x + b0.x, a0.y + b0.y, a0.z + b0.z, a0.w + b0.w);
            float4 v1 = make_float4(a1.x + b1.x, a1.y + b1.y, a1.z + b1.z, a1.w + b1.w);
            uint2 h0, l0, h1, l1;
            cvt4(v0, h0, l0);
            cvt4(v1, h1, l1);
            int ph = swz(row, j8 << 4);
            *(uint4*)(aH + ph) = make_uint4(h0.x, h0.y, h1.x, h1.y);
            *(uint4*)(aL + ph) = make_uint4(l0.x, l0.y, l1.x, l1.y);
        }
#pragma unroll
        for (int i = 0; i < 4; ++i) {
            int idx = (i << 8) + t;
            int plane = idx >> 9, rem = idx & 511;
            int nn = rem >> 3, j8 = rem & 7;
            const unsigned short* src = plane ? WTl : WTh;
            uint4 vv = *(const uint4*)&src[(size_t)(n0 + nn) * 512 + k0 + (j8 << 3)];
            *(uint4*)((plane ? wL : wH) + swz(nn, j8 << 4)) = vv;
        }
        __syncthreads();
#pragma unroll
        for (int kk = 0; kk < 2; ++kk) {
            int bc = (kk << 6) + (kg << 4);
            int ar = (w << 4) + lr;
            short8 a_h = *(const short8*)(aH + swz(ar, bc));
            short8 a_l = *(const short8*)(aL + swz(ar, bc));
#pragma unroll
            for (int f = 0; f < 4; ++f) {
                short8 b_h = *(const short8*)(wH + swz((f << 4) + lr, bc));
                short8 b_l = *(const short8*)(wL + swz((f << 4) + lr, bc));
                acc[f] = __builtin_amdgcn_mfma_f32_16x16x32_bf16(a_h, b_h, acc[f], 0, 0, 0);
                acc[f] = __builtin_amdgcn_mfma_f32_16x16x32_bf16(a_l, b_h, acc[f], 0, 0, 0);
                acc[f] = __builtin_amdgcn_mfma_f32_16x16x32_bf16(a_h, b_l, acc[f], 0, 0, 0);
            }
        }
    }

    const int mbase = m0 + (w << 4) + (kg << 2);
#pragma unroll
    for (int f = 0; f < 4; ++f) {
        int n = n0 + (f << 4) + lr;
        float bv = bias[n];
#pragma unroll
        for (int e = 0; e < 4; ++e)
            out0[(size_t)(mbase + e) * 512 + n] = acc[f][e] + bv;
    }
}

// ---------------------------------------------------------------------------
// K2: flash-style logits (round-13 verified) + optional bf16 raw store.
// useBf16=1: raw logits stored as bf16 to rawh (134 MB, L3-resident) instead
// of fp32 to attn — halves the intermediate's write+read traffic.
// ---------------------------------------------------------------------------
__global__ __launch_bounds__(512, 4) void logits_flash(
    const unsigned short* __restrict__ qh_g, const unsigned short* __restrict__ ql_g,
    const unsigned short* __restrict__ kh_g, const unsigned short* __restrict__ kl_g,
    const unsigned short* __restrict__ relh_g,
    float* __restrict__ attn, unsigned short* __restrict__ rawh, int useBf16,
    float2* __restrict__ stats)
{
    __shared__ char smem[59136];
    char* kh = smem;                              // [128][64] swz bf16 (16 KB)
    char* kl = smem + 16384;
    char* bandP = smem + 32768;                   // band [192][64] swz bf16
    unsigned short* Pt = (unsigned short*)(smem + 32768);  // [192][66] bf16, overlays band
    float* part_m = (float*)(smem + 58112);       // [2][64]
    float* part_z = (float*)(smem + 58624);       // [2][64]

    const int t = threadIdx.x;
    const int bh = blockIdx.y;
    int ib = blockIdx.x; if (bh & 8) ib = 31 - ib;
    const int i0 = ib << 6;
    const int lane = t & 63, w = t >> 6;
    const int wr = w >> 1, wc = w & 1;
    const int lr = lane & 15, kg = lane >> 4;
    const int irow = (wr << 4) + lr;

    const size_t qoff = ((size_t)bh * 2048 + i0 + irow) * 64;
    const short8 aH0 = *(const short8*)(qh_g + qoff + (kg << 3));
    const short8 aH1 = *(const short8*)(qh_g + qoff + 32 + (kg << 3));
    const short8 aL0 = *(const short8*)(ql_g + qoff + (kg << 3));
    const short8 aL1 = *(const short8*)(ql_g + qoff + 32 + (kg << 3));

    float rm = -3.0e38f, rz = 0.f;

    const unsigned short* khb = kh_g + (size_t)bh * 2048 * 64;
    const unsigned short* klb = kl_g + (size_t)bh * 2048 * 64;
    const size_t obase = ((size_t)bh * 2048 + i0) * 2048;

    for (int jt = 0; jt < 16; ++jt) {
        const int j0 = jt << 7;
        const bool anyRel = (j0 <= i0 + 63);
        const int m0 = 1984 - i0 + j0;
        __syncthreads();   // prior iter LDS reads done; prev parts visible
        if (jt > 0 && t < 64) {   // wave0: combine prev tile's stats
            float m1 = part_m[t], m2 = part_m[64 + t];
            float z1 = part_z[t], z2 = part_z[64 + t];
            float tm = fmaxf(m1, m2);
            float tz = z1 * __expf((m1 - tm) * 0.125f) + z2 * __expf((m2 - tm) * 0.125f);
            float mn = fmaxf(rm, tm);
            rz = rz * __expf((rm - mn) * 0.125f) + tz * __expf((tm - mn) * 0.125f);
            rm = mn;
        }
        {
            int rr = t >> 2, gp = (t & 3) << 1;
            const unsigned short* s0 = khb + (size_t)(j0 + rr) * 64 + (gp << 3);
            *(uint4*)(kh + swz(rr, gp << 4)) = *(const uint4*)s0;
            *(uint4*)(kh + swz(rr, (gp + 1) << 4)) = *(const uint4*)(s0 + 8);
            const unsigned short* s1 = klb + (size_t)(j0 + rr) * 64 + (gp << 3);
            *(uint4*)(kl + swz(rr, gp << 4)) = *(const uint4*)s1;
            *(uint4*)(kl + swz(rr, (gp + 1) << 4)) = *(const uint4*)(s1 + 8);
        }
        if (anyRel) {
#pragma unroll
            for (int i = 0; i < 3; ++i) {
                int idx = (i << 9) + t;
                int row = idx >> 3, g = idx & 7;
                int m = m0 + row; if (m > 2047) m = 2047;
                *(uint4*)(bandP + swz(row, g << 4)) = *(const uint4*)(relh_g + (size_t)m * 64 + (g << 3));
            }
        }
        __syncthreads();

        f32x4 acc[4];
#pragma unroll
        for (int cf = 0; cf < 4; ++cf) {
            int krow = (wc << 6) + (cf << 4) + lr;
            short8 bH0 = *(const short8*)(kh + swz(krow, kg << 4));
            short8 bH1 = *(const short8*)(kh + swz(krow, 64 + (kg << 4)));
            short8 bL0 = *(const short8*)(kl + swz(krow, kg << 4));
            short8 bL1 = *(const short8*)(kl + swz(krow, 64 + (kg << 4)));
            f32x4 c = {0.f, 0.f, 0.f, 0.f};
            c = __builtin_amdgcn_mfma_f32_16x16x32_bf16(bH0, aH0, c, 0, 0, 0);
            c = __builtin_amdgcn_mfma_f32_16x16x32_bf16(bH1, aH1, c, 0, 0, 0);
            c = __builtin_amdgcn_mfma_f32_16x16x32_bf16(bH0, aL0, c, 0, 0, 0);
            c = __builtin_amdgcn_mfma_f32_16x16x32_bf16(bH1, aL1, c, 0, 0, 0);
            c = __builtin_amdgcn_mfma_f32_16x16x32_bf16(bL0, aH0, c, 0, 0, 0);
            c = __builtin_amdgcn_mfma_f32_16x16x32_bf16(bL1, aH1, c, 0, 0, 0);
            acc[cf] = c;
        }
        if (anyRel) {
            f32x4 pr[6];
#pragma unroll
            for (int q = 0; q < 6; ++q) {
                int ff = (wc ? 6 : 0) + q;
                int brow = (ff << 4) + lr;
                short8 rb0 = *(const short8*)(bandP + swz(brow, kg << 4));
                short8 rb1 = *(const short8*)(bandP + swz(brow, 64 + (kg << 4)));
                f32x4 c = {0.f, 0.f, 0.f, 0.f};
                c = __builtin_amdgcn_mfma_f32_16x16x32_bf16(rb0, aH0, c, 0, 0, 0);
                c = __builtin_amdgcn_mfma_f32_16x16x32_bf16(rb1, aH1, c, 0, 0, 0);
                pr[q] = c;
            }
            __syncthreads();
#pragma unroll
            for (int q = 0; q < 6; ++q) {
                int ff = (wc ? 6 : 0) + q;
#pragma unroll
                for (int e = 0; e < 4; ++e)
                    Pt[((ff << 4) + (kg << 2) + e) * 66 + irow] = f2bf(pr[q][e]);
            }
            __syncthreads();
        }

        float rowmax = -3.0e38f;
#pragma unroll
        for (int cf = 0; cf < 4; ++cf) {
            int jl0 = (wc << 6) + (cf << 4) + (kg << 2);
            f32x4 a = acc[cf];
#pragma unroll
            for (int e = 0; e < 4; ++e) {
                int jl = jl0 + e;
                if (anyRel && (jl - irow) <= (i0 - j0))
                    a[e] += bf2f(Pt[(jl + 63 - irow) * 66 + irow]);
            }
            acc[cf] = a;
            size_t oidx = obase + (size_t)irow * 2048 + j0 + jl0;
            if (useBf16) {
                *(uint2*)&rawh[oidx] = make_uint2(
                    (unsigned)f2bf(a[0]) | ((unsigned)f2bf(a[1]) << 16),
                    (unsigned)f2bf(a[2]) | ((unsigned)f2bf(a[3]) << 16));
            } else {
                *(float4*)&attn[oidx] = make_float4(a[0], a[1], a[2], a[3]);
            }
            rowmax = fmaxf(rowmax, fmaxf(fmaxf(a[0], a[1]), fmaxf(a[2], a[3])));
        }
        rowmax = fmaxf(rowmax, __shfl_xor(rowmax, 16, 64));
        rowmax = fmaxf(rowmax, __shfl_xor(rowmax, 32, 64));
        float zs = 0.f;
#pragma unroll
        for (int cf = 0; cf < 4; ++cf)
#pragma unroll
            for (int e = 0; e < 4; ++e)
                zs += __expf((acc[cf][e] - rowmax) * 0.125f);
        zs += __shfl_xor(zs, 16, 64);
        zs += __shfl_xor(zs, 32, 64);
        if (lane < 16) {
            part_m[(wc << 6) + irow] = rowmax;
            part_z[(wc << 6) + irow] = zs;
        }
    }
    __syncthreads();
    if (t < 64) {
        float m1 = part_m[t], m2 = part_m[64 + t];
        float z1 = part_z[t], z2 = part_z[64 + t];
        float tm = fmaxf(m1, m2);
        float tz = z1 * __expf((m1 - tm) * 0.125f) + z2 * __expf((m2 - tm) * 0.125f);
        float mn = fmaxf(rm, tm);
        rz = rz * __expf((rm - mn) * 0.125f) + tz * __expf((tm - mn) * 0.125f);
        rm = mn;
        stats[bh * 2048 + i0 + t] = make_float2(rm, 1.0f / rz);
    }
}

// ---------------------------------------------------------------------------
// K4: fused normalize + attn write + PV MFMA — round-13 i-tile-64 geometry
// (verified 163.5 us). useBf16=1: raw logits read from bf16 rawh (L3-resident)
// instead of fp32 attn; normalized fp32 attn written either way.
// ---------------------------------------------------------------------------
__global__ __launch_bounds__(256) void pv_fused(float* __restrict__ attn,
                                                const unsigned short* __restrict__ rawh,
                                                int useBf16,
                                                const unsigned short* __restrict__ vTh,
                                                const unsigned short* __restrict__ vTl,
                                                const float2* __restrict__ stats,
                                                float* __restrict__ pO)
{
    __shared__ char smem[33280];
    char* pH = smem;              // [64][64] bf16 swz (8 KB)
    char* pL = smem + 8192;
    char* vH = smem + 16384;      // [64][64] bf16 swz (8 KB)
    char* vL = smem + 24576;
    float2* sm = (float2*)(smem + 32768);  // [64] row stats

    const int t = threadIdx.x;
    const int i0 = blockIdx.x << 6;
    const int bh = blockIdx.y;
    const int jc = blockIdx.z;
    const int jc0 = jc << 10;
    const int lane = t & 63, w = t >> 6;
    const int lr = lane & 15, kg = lane >> 4;

    float* ab = attn + ((size_t)bh * 2048 + i0) * 2048;
    const unsigned short* rb = rawh + ((size_t)bh * 2048 + i0) * 2048;
    const unsigned short* vhb = vTh + (size_t)bh * 64 * 2048;
    const unsigned short* vlb = vTl + (size_t)bh * 64 * 2048;

    if (t < 64) sm[t] = stats[bh * 2048 + i0 + t];
    __syncthreads();

    f32x4 acc[4];
#pragma unroll
    for (int f = 0; f < 4; ++f) acc[f] = {0.f, 0.f, 0.f, 0.f};

    for (int j0 = jc0; j0 < jc0 + 1024; j0 += 64) {
        if (j0 != jc0) __syncthreads();
        // stage p (64 rows x 64 cols): load raw, normalize, write attn, cvt hi/lo
#pragma unroll
        for (int i = 0; i < 4; ++i) {
            int idx = (i << 8) + t;
            int row = idx >> 4, c4 = idx & 15;
            size_t go = (size_t)row * 2048 + j0 + (c4 << 2);
            float4 x;
            if (useBf16) {
                uint2 rv = *(const uint2*)&rb[go];
                x = make_float4(bf2f((unsigned short)(rv.x & 0xffff)),
                                bf2f((unsigned short)(rv.x >> 16)),
                                bf2f((unsigned short)(rv.y & 0xffff)),
                                bf2f((unsigned short)(rv.y >> 16)));
            } else {
                x = *(const float4*)&ab[go];
            }
            float2 s2 = sm[row];
            float4 p;
            p.x = __expf((x.x - s2.x) * 0.125f) * s2.y;
            p.y = __expf((x.y - s2.x) * 0.125f) * s2.y;
            p.z = __expf((x.z - s2.x) * 0.125f) * s2.y;
            p.w = __expf((x.w - s2.x) * 0.125f) * s2.y;
            *(float4*)&ab[go] = p;
            uint2 hi, lo; cvt4(p, hi, lo);
            int ph = swz(row, c4 << 3);
            *(uint2*)(pH + ph) = hi;
            *(uint2*)(pL + ph) = lo;
        }
        // stage v^T chunk (64 d x 64 j, both planes): direct uint4 copies
#pragma unroll
        for (int i = 0; i < 4; ++i) {
            int idx = (i << 8) + t;
            int plane = idx >> 9, rem = idx & 511;
            int d = rem >> 3, g8 = rem & 7;
            const unsigned short* src = (plane ? vlb : vhb) + (size_t)d * 2048 + j0 + (g8 << 3);
            *(uint4*)((plane ? vL : vH) + swz(d, g8 << 4)) = *(const uint4*)src;
        }
        __syncthreads();
#pragma unroll
        for (int kk = 0; kk < 2; ++kk) {
            int bc = (kk << 6) + (kg << 4);
            int ar = (w << 4) + lr;
            short8 a_h = *(const short8*)(pH + swz(ar, bc));
            short8 a_l = *(const short8*)(pL + swz(ar, bc));
#pragma unroll
            for (int f = 0; f < 4; ++f) {
                short8 b_h = *(const short8*)(vH + swz((f << 4) + lr, bc));
                short8 b_l = *(const short8*)(vL + swz((f << 4) + lr, bc));
                acc[f] = __builtin_amdgcn_mfma_f32_16x16x32_bf16(a_h, b_h, acc[f], 0, 0, 0);
                acc[f] = __builtin_amdgcn_mfma_f32_16x16x32_bf16(a_l, b_h, acc[f], 0, 0, 0);
                acc[f] = __builtin_amdgcn_mfma_f32_16x16x32_bf16(a_h, b_l, acc[f], 0, 0, 0);
            }
        }
    }
    // partial O: pO[jc][bh][i][d]
#pragma unroll
    for (int f = 0; f < 4; ++f) {
#pragma unroll
        for (int e = 0; e < 4; ++e) {
            int m = i0 + (w << 4) + (kg << 2) + e;
            pO[(size_t)jc * 2097152 + ((size_t)bh * 2048 + m) * 64 + (f << 4) + lr] = acc[f][e];
        }
    }
}

// ---------------------------------------------------------------------------
extern "C" void kernel_launch(void* const* d_in, const int* in_sizes, int n_in,
                              void* d_out, int out_size, void* d_ws, size_t ws_size,
                              hipStream_t stream)
{
    const float* q_in = (const float*)d_in[0];
    const float* k_in = (const float*)d_in[1];
    const float* v_in = (const float*)d_in[2];
    const float* Wq   = (const float*)d_in[3];
    const float* bq   = (const float*)d_in[4];
    const float* Wk   = (const float*)d_in[5];
    const float* bk   = (const float*)d_in[6];
    const float* Wv   = (const float*)d_in[7];
    const float* bv   = (const float*)d_in[8];
    const float* Wo   = (const float*)d_in[9];
    const float* bo   = (const float*)d_in[10];
    const float* rel  = (const float*)d_in[11];

    float* out0 = (float*)d_out;
    float* attn = out0 + 2097152;

    float* ws = (float*)d_ws;
    // bf16 planes: each 2,097,152 ushorts = 1,048,576 FLOATS of ws
    unsigned short* qh = (unsigned short*)ws;                 // floats [0, 1M)
    unsigned short* ql = qh + 2097152;                        // floats [1M, 2M)
    unsigned short* kh = (unsigned short*)(ws + 2097152);     // floats [2M, 3M)
    unsigned short* kl = kh + 2097152;                        // floats [3M, 4M)
    unsigned short* vTh = (unsigned short*)(ws + 4194304);    // floats [4M, 5M)
    unsigned short* vTl = vTh + 2097152;                      // floats [5M, 6M)
    unsigned short* wt = (unsigned short*)(ws + 6291456);     // floats [6M, 7M)
    unsigned short* relh = (unsigned short*)(ws + 7340032);   // floats [7340032, 7405568)
    float2* stats = (float2*)(ws + 7405568);                  // floats [7405568, 7471104)
    unsigned short* rawh = (unsigned short*)(ws + 7471104);   // 67,108,864 ushorts = floats [7471104, 41025536)
    float* pO = ws;                                           // 2 x 2,097,152 floats over dead q/k planes

    // bf16 raw-logit path needs 164.1 MB of ws; deterministic per-problem.
    const int useBf16 = (ws_size >= 164102144ULL) ? 1 : 0;

    wt_prep4<<<dim3(16, 16, 4), 256, 0, stream>>>(Wq, Wk, Wv, Wo, wt);
    rel_prep<<<64, 256, 0, stream>>>(rel, relh);

    gemm_qkv<<<dim3(8, 64, 3), 256, 0, stream>>>(q_in, k_in, v_in, wt,
                                                 bq, bk, bv,
                                                 qh, ql, kh, kl, vTh, vTl);

    logits_flash<<<dim3(32, 16), 512, 0, stream>>>(qh, ql, kh, kl, relh,
                                                   attn, rawh, useBf16, stats);
    pv_fused<<<dim3(32, 16, 2), 256, 0, stream>>>(attn, rawh, useBf16,
                                                  vTh, vTl, stats, pO);

    gemm_out<<<dim3(8, 64), 256, 0, stream>>>(pO,
                                              wt + 6 * 262144, wt + 7 * 262144,
                                              bo, out0);
}